// Round 3
// baseline (95.315 us; speedup 1.0000x reference)
//
#include <hip/hip_runtime.h>
#include <math.h>

#define HB 256   // hidden
#define UB 128   // attention units
#define BB 16    // batch
#define TD 128   // decoder steps
#define TE 1024  // encoder steps
#define TT 4     // t-rows per score thread

// exp(2*clamp(w,-10,10)) : staged operand for tanh factorization
// tanh(a+e) = 1 - 2/(exp(2a)exp(2e)+1).
// Clamp +-10 guarantees pair products (x+1)(y+1) <= 5.6e34 < f32 max;
// N(0,1) data never reaches |w|>10 so accuracy is unaffected.
__device__ __forceinline__ float exp2c(float w) {
    float t = fminf(fmaxf(w, -10.f), 10.f);
    return __expf(2.f * t);
}

// P = exp(2(X W + b)), X:[rows,HB] W:[HB,UB].
// Block 256 thr: 32 rows staged in LDS; thread = (ut=tid&15 -> 8 u, rt=tid>>4 -> 2 rows).
// Per 4-h group: 8 W float4 (coalesced/merged), 2 broadcast ds_read_b128, 64 FMA
// -> LDS reads/FMA = 1/32 (under the 1/24 per-CU LDS-pipe budget).
// __syncthreads every 64 h keeps all 8 waves on one 32 KB L1-resident W panel.
template<int TRANS>
__global__ __launch_bounds__(256) void proj_exp3(
    const float* __restrict__ X, const float* __restrict__ W,
    const float* __restrict__ bias, float* __restrict__ out, int seq) {
    constexpr int R = 32;
    __shared__ float xs[R][HB + 4];   // +4 pad: rows 2 apart -> 8 banks apart
    const int tid = threadIdx.x;
    const long row0 = (long)blockIdx.x * R;

    {   // stage 32x256 floats, coalesced float4
        const float4* src = reinterpret_cast<const float4*>(X + row0 * HB);
        #pragma unroll
        for (int i = 0; i < 8; ++i) {
            int idx = i * 256 + tid;
            int r = idx >> 6, c = idx & 63;
            *reinterpret_cast<float4*>(&xs[r][c * 4]) = src[idx];
        }
    }
    __syncthreads();

    const int ut = tid & 15;
    const int rt = tid >> 4;
    const int u0 = ut * 8;
    const int r0 = rt * 2;

    float acc[2][8];
    #pragma unroll
    for (int r = 0; r < 2; ++r)
        #pragma unroll
        for (int j = 0; j < 8; ++j) acc[r][j] = 0.f;

    for (int hc = 0; hc < HB; hc += 64) {
        #pragma unroll 2
        for (int h = hc; h < hc + 64; h += 4) {
            float4 wa[4], wb[4];
            #pragma unroll
            for (int k = 0; k < 4; ++k) {
                wa[k] = *reinterpret_cast<const float4*>(&W[(h + k) * UB + u0]);
                wb[k] = *reinterpret_cast<const float4*>(&W[(h + k) * UB + u0 + 4]);
            }
            #pragma unroll
            for (int r = 0; r < 2; ++r) {
                float4 x4 = *reinterpret_cast<const float4*>(&xs[r0 + r][h]);
                float xk[4] = {x4.x, x4.y, x4.z, x4.w};
                #pragma unroll
                for (int k = 0; k < 4; ++k) {
                    acc[r][0] = fmaf(xk[k], wa[k].x, acc[r][0]);
                    acc[r][1] = fmaf(xk[k], wa[k].y, acc[r][1]);
                    acc[r][2] = fmaf(xk[k], wa[k].z, acc[r][2]);
                    acc[r][3] = fmaf(xk[k], wa[k].w, acc[r][3]);
                    acc[r][4] = fmaf(xk[k], wb[k].x, acc[r][4]);
                    acc[r][5] = fmaf(xk[k], wb[k].y, acc[r][5]);
                    acc[r][6] = fmaf(xk[k], wb[k].z, acc[r][6]);
                    acc[r][7] = fmaf(xk[k], wb[k].w, acc[r][7]);
                }
            }
        }
        __syncthreads();   // keep waves on the same W panel (L1 locality)
    }

    float bv[8];
    #pragma unroll
    for (int j = 0; j < 8; ++j) bv[j] = bias[u0 + j];

    if (TRANS == 0) {
        #pragma unroll
        for (int r = 0; r < 2; ++r) {
            float o[8];
            #pragma unroll
            for (int j = 0; j < 8; ++j) o[j] = exp2c(acc[r][j] + bv[j]);
            float4* op = reinterpret_cast<float4*>(out + (row0 + r0 + r) * UB + u0);
            op[0] = make_float4(o[0], o[1], o[2], o[3]);
            op[1] = make_float4(o[4], o[5], o[6], o[7]);
        }
    } else {
        const long bq = row0 / seq;
        const long s0 = row0 % seq;
        #pragma unroll
        for (int j = 0; j < 8; ++j) {
            float* op = out + (bq * UB + u0 + j) * (long)seq + s0 + r0;
            float2 o = make_float2(exp2c(acc[0][j] + bv[j]), exp2c(acc[1][j] + bv[j]));
            *reinterpret_cast<float2*>(op) = o;
        }
    }
}

// scores + fused softmax. 1024 thr = 16 waves; thread owns 1 s-column x TT=4 rows.
// Grid 512 -> 32 waves/CU (100% occupancy).
// Pairwise division merge (exact): Vu/X + Vw/Y = (Vu*Y + Vw*X)/(X*Y)
// -> 3 VALU + 0.5 rcp per element instead of 2 VALU + 1 rcp (trans-pipe halved).
__global__ __launch_bounds__(1024) void score_softmax3(
    const float* __restrict__ Ea,   // [B*TD, UB]
    const float* __restrict__ EbT,  // [B, UB, TE]
    const float* __restrict__ V,    // [UB]
    float* __restrict__ out) {      // [B, TD, TE]
    const int tid = threadIdx.x;
    const int w = tid >> 6, l = tid & 63;
    const int i = blockIdx.x;
    const int b  = 2 * (i & 7) + ((i >> 3) >> 5);   // XCD-pinned: xcd gets b{2x,2x+1}
    const int t0 = ((i >> 3) & 31) * TT;
    const int s  = tid;

    const float* __restrict__ ap = Ea + ((long)b * TD + t0) * UB;   // wave-uniform
    const float* __restrict__ eb = EbT + ((long)b * UB) * TE + s;   // per-lane, coalesced

    float acc[TT] = {0.f, 0.f, 0.f, 0.f};

    for (int u = 0; u < UB; u += 4) {
        float4 v4 = *reinterpret_cast<const float4*>(V + u);
        float e0 = eb[(long)(u + 0) * TE];
        float e1 = eb[(long)(u + 1) * TE];
        float e2 = eb[(long)(u + 2) * TE];
        float e3 = eb[(long)(u + 3) * TE];
        #pragma unroll
        for (int t = 0; t < TT; ++t) {
            float4 a4 = *reinterpret_cast<const float4*>(ap + t * UB + u);
            float Xa = fmaf(a4.x, e0, 1.f), Ya = fmaf(a4.y, e1, 1.f);
            float Na = fmaf(v4.x, Ya, v4.y * Xa);
            acc[t] = fmaf(Na, __builtin_amdgcn_rcpf(Xa * Ya), acc[t]);
            float Xb = fmaf(a4.z, e2, 1.f), Yb = fmaf(a4.w, e3, 1.f);
            float Nb = fmaf(v4.z, Yb, v4.w * Xb);
            acc[t] = fmaf(Nb, __builtin_amdgcn_rcpf(Xb * Yb), acc[t]);
        }
    }

    float sc[TT];
    #pragma unroll
    for (int t = 0; t < TT; ++t) sc[t] = -2.f * acc[t];

    __shared__ float red[TT][16];
    #pragma unroll
    for (int t = 0; t < TT; ++t) {
        float x = sc[t];
        #pragma unroll
        for (int off = 32; off > 0; off >>= 1) x = fmaxf(x, __shfl_xor(x, off, 64));
        if (l == 0) red[t][w] = x;
    }
    __syncthreads();
    float m[TT];
    #pragma unroll
    for (int t = 0; t < TT; ++t) {
        float x = red[t][0];
        #pragma unroll
        for (int k = 1; k < 16; ++k) x = fmaxf(x, red[t][k]);
        m[t] = x;
    }
    __syncthreads();   // red reused below
    #pragma unroll
    for (int t = 0; t < TT; ++t) {
        sc[t] = __expf(sc[t] - m[t]);
        float x = sc[t];
        #pragma unroll
        for (int off = 32; off > 0; off >>= 1) x += __shfl_xor(x, off, 64);
        if (l == 0) red[t][w] = x;
    }
    __syncthreads();
    #pragma unroll
    for (int t = 0; t < TT; ++t) {
        float x = red[t][0];
        #pragma unroll
        for (int k = 1; k < 16; ++k) x += red[t][k];
        out[((long)b * TD + t0 + t) * TE + s] = sc[t] * (1.f / x);
    }
}

extern "C" void kernel_launch(void* const* d_in, const int* in_sizes, int n_in,
                              void* d_out, int out_size, void* d_ws, size_t ws_size,
                              hipStream_t stream) {
    const float* dec = (const float*)d_in[0];
    const float* enc = (const float*)d_in[1];
    const float* W1  = (const float*)d_in[2];
    const float* b1  = (const float*)d_in[3];
    const float* W2  = (const float*)d_in[4];
    const float* b2  = (const float*)d_in[5];
    const float* V   = (const float*)d_in[6];
    // d_in[7] = bv : softmax-invariant, unused
    float* out = (float*)d_out;

    float* Ea  = (float*)d_ws;                 // [B*TD, UB]  1 MB
    float* EbT = Ea + (long)BB * TD * UB;      // [B, UB, TE] 8 MB

    proj_exp3<0><<<BB * TD / 32, 256, 0, stream>>>(dec, W1, b1, Ea, TD);
    proj_exp3<1><<<BB * TE / 32, 256, 0, stream>>>(enc, W2, b2, EbT, TE);
    score_softmax3<<<BB * (TD / TT), 1024, 0, stream>>>(Ea, EbT, V, out);
}

// Round 4
// 94.717 us; speedup vs baseline: 1.0063x; 1.0063x over previous
//
#include <hip/hip_runtime.h>
#include <math.h>

#define HB 256   // hidden
#define UB 128   // attention units
#define BB 16    // batch
#define TD 128   // decoder steps
#define TE 1024  // encoder steps
#define TT 4     // t-rows per score thread

#define CLAMP_W 7.0f
#define L2E2 2.8853900817779268f        // 2*log2(e)
#define ALPHA 1.52587890625e-05f        // 2^-16 (folded into Ea)
#define NEG2ALPHA (-3.0517578125e-05f)  // -2*ALPHA

// staged operand: exp2(2*log2e*clamp(w,+-7) + shift).
// tanh(a+e) = 1 - 2/(exp(2a)exp(2e)+1); clamp +-7 is never hit by N(0,1)-ish
// data (max |w| ~ 6) so exact; shift=-16 scales Ea by 2^-16 so the 4-way
// merged denominator X0'X1'X2'X3' <= 2^122... actually <= 2^98, overflow-safe.
__device__ __forceinline__ float stage_exp(float w, float shift) {
    float t = fminf(fmaxf(w, -CLAMP_W), CLAMP_W);
    return exp2f(fmaf(t, L2E2, shift));
}

// P = stage_exp(X W + b). Thread: 8 u x RPT rows; block 256 thr = 16 u-threads
// x 16 row-threads -> 16*RPT rows/block. W double-buffered in registers
// (prefetch h+4 while computing h); xs (LDS) prefetched the same way.
// TRANS=0: out[row][u] row-major (Ea, shift=-16).
// TRANS=1: tiled Eb4 layout [b][st][u4][l][4] (shift=0), st=s>>6, l=s&63.
template<int RPT, int TRANS>
__global__ __launch_bounds__(256) void proj_v4(
    const float* __restrict__ X, const float* __restrict__ W,
    const float* __restrict__ bias, float* __restrict__ out) {
    constexpr int R = 16 * RPT;
    __shared__ float xs[R][HB + 4];
    const int tid = threadIdx.x;
    const long row0 = (long)blockIdx.x * R;

    {   // stage R x 256 floats, coalesced float4
        const float4* src = reinterpret_cast<const float4*>(X + row0 * HB);
        #pragma unroll
        for (int i = 0; i < R * HB / 4 / 256; ++i) {
            int idx = i * 256 + tid;
            int r = idx >> 6, c = idx & 63;
            *reinterpret_cast<float4*>(&xs[r][c * 4]) = src[idx];
        }
    }
    __syncthreads();

    const int ut = tid & 15, rt = tid >> 4;
    const int u0 = ut * 8;
    const int r0 = rt * RPT;
    const float* wp = W + u0;

    float acc[RPT][8];
    #pragma unroll
    for (int r = 0; r < RPT; ++r)
        #pragma unroll
        for (int j = 0; j < 8; ++j) acc[r][j] = 0.f;

    float4 wa[4], wb[4], wna[4], wnb[4], xa[RPT], xna[RPT];
    #pragma unroll
    for (int k = 0; k < 4; ++k) {
        wa[k] = *reinterpret_cast<const float4*>(wp + k * UB);
        wb[k] = *reinterpret_cast<const float4*>(wp + k * UB + 4);
    }
    #pragma unroll
    for (int r = 0; r < RPT; ++r)
        xa[r] = *reinterpret_cast<const float4*>(&xs[r0 + r][0]);

    for (int h = 0; h < HB; h += 4) {
        const int hn = (h + 4 < HB) ? h + 4 : h;   // clamped re-load on last iter
        #pragma unroll
        for (int k = 0; k < 4; ++k) {
            wna[k] = *reinterpret_cast<const float4*>(wp + (hn + k) * UB);
            wnb[k] = *reinterpret_cast<const float4*>(wp + (hn + k) * UB + 4);
        }
        #pragma unroll
        for (int r = 0; r < RPT; ++r)
            xna[r] = *reinterpret_cast<const float4*>(&xs[r0 + r][hn]);

        #pragma unroll
        for (int r = 0; r < RPT; ++r) {
            const float xk[4] = {xa[r].x, xa[r].y, xa[r].z, xa[r].w};
            #pragma unroll
            for (int k = 0; k < 4; ++k) {
                acc[r][0] = fmaf(xk[k], wa[k].x, acc[r][0]);
                acc[r][1] = fmaf(xk[k], wa[k].y, acc[r][1]);
                acc[r][2] = fmaf(xk[k], wa[k].z, acc[r][2]);
                acc[r][3] = fmaf(xk[k], wa[k].w, acc[r][3]);
                acc[r][4] = fmaf(xk[k], wb[k].x, acc[r][4]);
                acc[r][5] = fmaf(xk[k], wb[k].y, acc[r][5]);
                acc[r][6] = fmaf(xk[k], wb[k].z, acc[r][6]);
                acc[r][7] = fmaf(xk[k], wb[k].w, acc[r][7]);
            }
        }
        #pragma unroll
        for (int k = 0; k < 4; ++k) { wa[k] = wna[k]; wb[k] = wnb[k]; }
        #pragma unroll
        for (int r = 0; r < RPT; ++r) xa[r] = xna[r];
    }

    float bv[8];
    #pragma unroll
    for (int j = 0; j < 8; ++j) bv[j] = bias[u0 + j];

    if (TRANS == 0) {
        #pragma unroll
        for (int r = 0; r < RPT; ++r) {
            float o[8];
            #pragma unroll
            for (int j = 0; j < 8; ++j) o[j] = stage_exp(acc[r][j] + bv[j], -16.f);
            float4* op = reinterpret_cast<float4*>(out + (row0 + r0 + r) * UB + u0);
            op[0] = make_float4(o[0], o[1], o[2], o[3]);
            op[1] = make_float4(o[4], o[5], o[6], o[7]);
        }
    } else {
        float4* base = reinterpret_cast<float4*>(out);
        #pragma unroll
        for (int r = 0; r < RPT; ++r) {
            float o[8];
            #pragma unroll
            for (int j = 0; j < 8; ++j) o[j] = stage_exp(acc[r][j] + bv[j], 0.f);
            const long grow = row0 + r0 + r;
            const long bb = grow >> 10;            // / TE
            const int  s  = (int)(grow & (TE - 1));
            const int  st = s >> 6, l = s & 63;
            base[(((bb * 16) + st) * 32 + (ut * 2 + 0)) * 64 + l] =
                make_float4(o[0], o[1], o[2], o[3]);
            base[(((bb * 16) + st) * 32 + (ut * 2 + 1)) * 64 + l] =
                make_float4(o[4], o[5], o[6], o[7]);
        }
    }
}

// scores + fused softmax. 1024 thr = 16 waves; wave wv owns s-tile st=wv
// (s = wv*64 + lane). Eb4 tiled layout gives one dwordx4 per 4 u per thread
// with 1KB stride (imm-offset friendly); explicit e-prefetch rotation hides
// L2 latency. 4-way division merge (exact):
//   sum_{c=0..3} Vc/Xc = (N01*P23 + N23*P01) / (P01*P23),
//   N01 = V0*X1 + V1*X0, P01 = X0*X1 (etc.)
// -> 3.5 VALU + 0.25 rcp per element. X' carries the 2^-16 Ea scale;
// final score = -2*ALPHA * acc (softmax-shift-invariant terms dropped).
__global__ __launch_bounds__(1024) void score_softmax4(
    const float* __restrict__ Ea,    // [B*TD, UB], scaled by 2^-16
    const float4* __restrict__ Eb4,  // [B][16][32][64] float4
    const float* __restrict__ V,     // [UB]
    float* __restrict__ out) {       // [B, TD, TE]
    const int tid = threadIdx.x;
    const int wv = tid >> 6, l = tid & 63;
    const int i = blockIdx.x;
    const int b  = 2 * (i & 7) + ((i >> 3) >> 5);   // XCD-pinned batches
    const int t0 = ((i >> 3) & 31) * TT;

    const float* __restrict__ ap = Ea + ((long)b * TD + t0) * UB;     // uniform
    const float4* __restrict__ ep = Eb4 + ((long)(b * 16 + wv)) * 2048 + l;

    float acc[TT] = {0.f, 0.f, 0.f, 0.f};
    float4 e = ep[0];

    #pragma unroll 2
    for (int u4 = 0; u4 < 32; ++u4) {
        float4 en = ep[((u4 + 1) & 31) * 64];       // prefetch next (wraps, harmless)
        float4 v4 = *reinterpret_cast<const float4*>(V + u4 * 4);
        #pragma unroll
        for (int t = 0; t < TT; ++t) {
            float4 a4 = *reinterpret_cast<const float4*>(ap + t * UB + u4 * 4);
            float X0 = fmaf(a4.x, e.x, ALPHA);
            float X1 = fmaf(a4.y, e.y, ALPHA);
            float X2 = fmaf(a4.z, e.z, ALPHA);
            float X3 = fmaf(a4.w, e.w, ALPHA);
            float P01 = X0 * X1, P23 = X2 * X3;
            float N01 = fmaf(v4.x, X1, v4.y * X0);
            float N23 = fmaf(v4.z, X3, v4.w * X2);
            float N   = fmaf(N01, P23, N23 * P01);
            acc[t] = fmaf(N, __builtin_amdgcn_rcpf(P01 * P23), acc[t]);
        }
        e = en;
    }

    float sc[TT];
    #pragma unroll
    for (int t = 0; t < TT; ++t) sc[t] = NEG2ALPHA * acc[t];

    __shared__ float red[TT][16];
    #pragma unroll
    for (int t = 0; t < TT; ++t) {
        float x = sc[t];
        #pragma unroll
        for (int off = 32; off > 0; off >>= 1) x = fmaxf(x, __shfl_xor(x, off, 64));
        if (l == 0) red[t][wv] = x;
    }
    __syncthreads();
    float m[TT];
    #pragma unroll
    for (int t = 0; t < TT; ++t) {
        float x = red[t][0];
        #pragma unroll
        for (int k = 1; k < 16; ++k) x = fmaxf(x, red[t][k]);
        m[t] = x;
    }
    __syncthreads();
    #pragma unroll
    for (int t = 0; t < TT; ++t) {
        sc[t] = __expf(sc[t] - m[t]);
        float x = sc[t];
        #pragma unroll
        for (int off = 32; off > 0; off >>= 1) x += __shfl_xor(x, off, 64);
        if (l == 0) red[t][wv] = x;
    }
    __syncthreads();
    #pragma unroll
    for (int t = 0; t < TT; ++t) {
        float x = red[t][0];
        #pragma unroll
        for (int k = 1; k < 16; ++k) x += red[t][k];
        out[((long)b * TD + t0 + t) * TE + tid] = sc[t] * (1.f / x);
    }
}

extern "C" void kernel_launch(void* const* d_in, const int* in_sizes, int n_in,
                              void* d_out, int out_size, void* d_ws, size_t ws_size,
                              hipStream_t stream) {
    const float* dec = (const float*)d_in[0];
    const float* enc = (const float*)d_in[1];
    const float* W1  = (const float*)d_in[2];
    const float* b1  = (const float*)d_in[3];
    const float* W2  = (const float*)d_in[4];
    const float* b2  = (const float*)d_in[5];
    const float* V   = (const float*)d_in[6];
    // d_in[7] = bv : softmax-invariant, unused
    float* out = (float*)d_out;

    float* Ea  = (float*)d_ws;                 // [B*TD, UB]  1 MB (2^-16-scaled)
    float* Eb  = Ea + (long)BB * TD * UB;      // tiled [B][16][32][64][4]  8 MB

    proj_v4<1, 0><<<BB * TD / 16, 256, 0, stream>>>(dec, W1, b1, Ea);
    proj_v4<2, 1><<<BB * TE / 32, 256, 0, stream>>>(enc, W2, b2, Eb);
    score_softmax4<<<BB * (TD / TT), 1024, 0, stream>>>(
        Ea, (const float4*)Eb, V, out);
}

// Round 6
// 75.150 us; speedup vs baseline: 1.2683x; 1.2604x over previous
//
#include <hip/hip_runtime.h>
#include <math.h>

#define HB 256   // hidden
#define UB 128   // attention units
#define BB 16    // batch
#define TD 128   // decoder steps
#define TE 1024  // encoder steps

#define CLAMP_W 7.0f
#define L2E2 2.8853900817779268f        // 2*log2(e)
#define ALPHA 1.52587890625e-05f        // 2^-16 (folded into Ea)
#define NEG2ALPHA (-3.0517578125e-05f)  // -2*ALPHA

// staged operand: exp2(2*log2e*clamp(w,+-7) + shift); tanh(a+e)=1-2/(EaEb+1).
// clamp +-7 never triggers on this data (|w| <~ 6); shift=-16 scales Ea so the
// 4-way merged denominator stays < 2^98. Same numerics as round 4 (passed).
__device__ __forceinline__ float stage_exp(float w, float shift) {
    float t = fminf(fmaxf(w, -CLAMP_W), CLAMP_W);
    return exp2f(fmaf(t, L2E2, shift));
}

// ---------------- projections (dec + enc, one grid) ----------------
// 1-wave (64-thr) blocks. lane = row within a 64-row slab (X loads coalesced
// dwordx4); block owns u8-tile -> acc[8] in VGPRs; W/bias addresses are
// wave-uniform -> compiler emits s_load (scalar pipe, zero VMEM pressure).
// ut-major block order + slab-count % 8 == 0 pins all 16 u-tile re-reads of a
// slab to one XCD's L2. Outputs written in score layout [b][u4][pos][4].
#define DEC_SLABS 32                     // 2048 rows / 64
#define ENC_SLABS 256                    // 16384 rows / 64
#define DEC_BLOCKS (16 * DEC_SLABS)      // 512
#define ENC_BLOCKS (16 * ENC_SLABS)      // 4096

__global__ __launch_bounds__(64) void proj_v6(
    const float* __restrict__ dec, const float* __restrict__ enc,
    const float* __restrict__ W1, const float* __restrict__ b1,
    const float* __restrict__ W2, const float* __restrict__ b2,
    float* __restrict__ Ea, float* __restrict__ Eb) {
    const int blk = blockIdx.x;
    const bool is_dec = blk < DEC_BLOCKS;
    const int rel   = is_dec ? blk : blk - DEC_BLOCKS;
    const int nslab = is_dec ? DEC_SLABS : ENC_SLABS;
    const int ut    = rel / nslab;           // 0..15 (ut-major)
    const int slab  = rel - ut * nslab;
    const float* __restrict__ X    = is_dec ? dec : enc;
    const float* __restrict__ W    = is_dec ? W1 : W2;
    const float* __restrict__ bias = is_dec ? b1 : b2;

    const int l = threadIdx.x;               // 0..63 = row in slab
    const long row = (long)slab * 64 + l;
    const float* xr = X + row * HB;          // per-lane, coalesced across lanes
    const int u0 = ut * 8;

    float acc[8];
    #pragma unroll
    for (int j = 0; j < 8; ++j) acc[j] = 0.f;

    for (int h = 0; h < HB; h += 8) {        // 32 iters: 2 x-dwordx4 + 16 s_load4
        float4 x0 = *reinterpret_cast<const float4*>(xr + h);
        float4 x1 = *reinterpret_cast<const float4*>(xr + h + 4);
        float4 w[8][2];
        #pragma unroll
        for (int k = 0; k < 8; ++k) {        // uniform -> scalar loads
            w[k][0] = *reinterpret_cast<const float4*>(W + (h + k) * UB + u0);
            w[k][1] = *reinterpret_cast<const float4*>(W + (h + k) * UB + u0 + 4);
        }
        const float xk[8] = {x0.x, x0.y, x0.z, x0.w, x1.x, x1.y, x1.z, x1.w};
        #pragma unroll
        for (int k = 0; k < 8; ++k) {
            acc[0] = fmaf(xk[k], w[k][0].x, acc[0]);
            acc[1] = fmaf(xk[k], w[k][0].y, acc[1]);
            acc[2] = fmaf(xk[k], w[k][0].z, acc[2]);
            acc[3] = fmaf(xk[k], w[k][0].w, acc[3]);
            acc[4] = fmaf(xk[k], w[k][1].x, acc[4]);
            acc[5] = fmaf(xk[k], w[k][1].y, acc[5]);
            acc[6] = fmaf(xk[k], w[k][1].z, acc[6]);
            acc[7] = fmaf(xk[k], w[k][1].w, acc[7]);
        }
    }

    float4 bv0 = *reinterpret_cast<const float4*>(bias + u0);
    float4 bv1 = *reinterpret_cast<const float4*>(bias + u0 + 4);
    const float sh = is_dec ? -16.f : 0.f;
    float4 q0 = make_float4(stage_exp(acc[0] + bv0.x, sh), stage_exp(acc[1] + bv0.y, sh),
                            stage_exp(acc[2] + bv0.z, sh), stage_exp(acc[3] + bv0.w, sh));
    float4 q1 = make_float4(stage_exp(acc[4] + bv1.x, sh), stage_exp(acc[5] + bv1.y, sh),
                            stage_exp(acc[6] + bv1.z, sh), stage_exp(acc[7] + bv1.w, sh));

    if (is_dec) {                            // Ea [b][u4][t][4]
        const long bq = row >> 7;
        const int  t  = (int)(row & (TD - 1));
        float4* dst = reinterpret_cast<float4*>(Ea);
        dst[(bq * 32 + ut * 2 + 0) * TD + t] = q0;
        dst[(bq * 32 + ut * 2 + 1) * TD + t] = q1;
    } else {                                 // Eb [b][u4][s][4]
        const long bq = row >> 10;
        const int  s  = (int)(row & (TE - 1));
        float4* dst = reinterpret_cast<float4*>(Eb);
        dst[(bq * 32 + ut * 2 + 0) * TE + s] = q0;
        dst[(bq * 32 + ut * 2 + 1) * TE + s] = q1;
    }
}

// ---------------- scores + fused softmax ----------------
// Grid 256 (XCD-pinned b), 1024 thr = 16 waves. Thread: s = tid, TT=8 t-rows.
// Two independent e-streams (u4, u4+16) + unroll 2 -> 4 coalesced float4 loads
// in flight; a-tile (contiguous 128B in Ea[b][u4][t][4]) + V are block-uniform
// -> compiler scalar loads (proven: R3/R4 SGPR=80). 4-way exact division merge.
__global__ __launch_bounds__(1024) void score_v6(
    const float* __restrict__ Ea4,   // [B][32][TD][4], 2^-16-scaled
    const float4* __restrict__ Eb4,  // [B][32][TE]
    const float* __restrict__ V,     // [UB]
    float* __restrict__ out) {       // [B, TD, TE]
    const int tid = threadIdx.x;
    const int wv = tid >> 6, l = tid & 63;
    const int i = blockIdx.x;
    const int b  = 2 * (i & 7) + ((i >> 3) >> 4);
    const int t0 = ((i >> 3) & 15) * 8;

    const float*  ab = Ea4 + ((long)b * 32 * TD) * 4;   // + (u4*TD + t0)*4
    const float4* ep = Eb4 + (long)b * 32 * TE + tid;   // + u4*TE
    const float alphav = ALPHA;

    float acc[8];
    #pragma unroll
    for (int t = 0; t < 8; ++t) acc[t] = 0.f;

#define SCSTREAM(U4, E) do {                                              \
        const float* _a = ab + ((long)(U4) * TD + t0) * 4;                \
        float4 _v = *reinterpret_cast<const float4*>(V + (U4) * 4);       \
        _Pragma("unroll")                                                 \
        for (int t = 0; t < 8; ++t) {                                     \
            float4 a4 = *reinterpret_cast<const float4*>(_a + t * 4);     \
            float X0 = fmaf(a4.x, (E).x, alphav);                         \
            float X1 = fmaf(a4.y, (E).y, alphav);                         \
            float X2 = fmaf(a4.z, (E).z, alphav);                         \
            float X3 = fmaf(a4.w, (E).w, alphav);                         \
            float P01 = X0 * X1, P23 = X2 * X3;                           \
            float N01 = fmaf(_v.x, X1, _v.y * X0);                        \
            float N23 = fmaf(_v.z, X3, _v.w * X2);                        \
            float N   = fmaf(N01, P23, N23 * P01);                        \
            acc[t] = fmaf(N, __builtin_amdgcn_rcpf(P01 * P23), acc[t]);   \
        }                                                                 \
    } while (0)

    #pragma unroll 2
    for (int u4 = 0; u4 < 16; ++u4) {
        float4 e0 = ep[(long)u4 * TE];
        float4 e1 = ep[(long)(u4 + 16) * TE];
        SCSTREAM(u4, e0);
        SCSTREAM(u4 + 16, e1);
    }
#undef SCSTREAM

    float sc[8];
    #pragma unroll
    for (int t = 0; t < 8; ++t) sc[t] = NEG2ALPHA * acc[t];

    __shared__ float red[8][16];
    #pragma unroll
    for (int t = 0; t < 8; ++t) {
        float x = sc[t];
        #pragma unroll
        for (int off = 32; off > 0; off >>= 1) x = fmaxf(x, __shfl_xor(x, off, 64));
        if (l == 0) red[t][wv] = x;
    }
    __syncthreads();
    float m[8];
    #pragma unroll
    for (int t = 0; t < 8; ++t) {
        float x = red[t][0];
        #pragma unroll
        for (int k = 1; k < 16; ++k) x = fmaxf(x, red[t][k]);
        m[t] = x;
    }
    __syncthreads();
    #pragma unroll
    for (int t = 0; t < 8; ++t) {
        sc[t] = __expf(sc[t] - m[t]);
        float x = sc[t];
        #pragma unroll
        for (int off = 32; off > 0; off >>= 1) x += __shfl_xor(x, off, 64);
        if (l == 0) red[t][wv] = x;
    }
    __syncthreads();
    #pragma unroll
    for (int t = 0; t < 8; ++t) {
        float x = red[t][0];
        #pragma unroll
        for (int k = 1; k < 16; ++k) x += red[t][k];
        out[((long)b * TD + t0 + t) * TE + tid] = sc[t] * (1.f / x);
    }
}

extern "C" void kernel_launch(void* const* d_in, const int* in_sizes, int n_in,
                              void* d_out, int out_size, void* d_ws, size_t ws_size,
                              hipStream_t stream) {
    const float* dec = (const float*)d_in[0];
    const float* enc = (const float*)d_in[1];
    const float* W1  = (const float*)d_in[2];
    const float* b1  = (const float*)d_in[3];
    const float* W2  = (const float*)d_in[4];
    const float* b2  = (const float*)d_in[5];
    const float* V   = (const float*)d_in[6];
    // d_in[7] = bv : softmax-invariant, unused
    float* out = (float*)d_out;

    float* Ea = (float*)d_ws;                  // [B][32][TD][4]  1 MB
    float* Eb = Ea + (long)BB * 32 * TD * 4;   // [B][32][TE][4]  8 MB

    proj_v6<<<DEC_BLOCKS + ENC_BLOCKS, 64, 0, stream>>>(dec, enc, W1, b1, W2, b2, Ea, Eb);
    score_v6<<<256, 1024, 0, stream>>>(Ea, (const float4*)Eb, V, out);
}